// Round 13
// baseline (451.056 us; speedup 1.0000x reference)
//
#include <hip/hip_runtime.h>
#include <math.h>

// GAT 2-layer: N=100000, E=1600000 (+N self loops), F_IN=128, HID=64, HEADS=2,
// OUT_HEADS=1, NUM_CLASS=18, NEG_SLOPE=0.2
// Round 12: (1) stash padded to 136 entries (head offset 68) -- R11's 64-entry
// head offset aliased the same LDS banks (925k conflicts). (2) l1 hot loop:
// hi-feature unpack uses raw uint (skip the AND; <=2^-9 rel perturbation).
// (3) k_deg_init -> hipMemsetAsync; self-loop folded into scan (+1) and
// scatter (offset base 1). Slow deg>64 path re-gathers from global (no stashE).

#define NEG_SLOPE 0.2f

typedef unsigned short ushort_t;

// ---------------- wave reductions (64 lanes) ----------------
__device__ __forceinline__ float wmax(float v) {
    for (int o = 32; o; o >>= 1) v = fmaxf(v, __shfl_xor(v, o));
    return v;
}
__device__ __forceinline__ float wsum(float v) {
    for (int o = 32; o; o >>= 1) v += __shfl_xor(v, o);
    return v;
}

// ---------------- bf16 helpers (RNE) ----------------
__device__ __forceinline__ unsigned bfpack(float a, float b) {
    unsigned ua = __float_as_uint(a);
    unsigned ub = __float_as_uint(b);
    ua = (ua + 0x7fffu + ((ua >> 16) & 1u)) >> 16;
    ub = (ub + 0x7fffu + ((ub >> 16) & 1u)) & 0xffff0000u;
    return ua | ub;
}
__device__ __forceinline__ ushort_t bf16of(float a) {
    unsigned ua = __float_as_uint(a);
    return (ushort_t)((ua + 0x7fffu + ((ua >> 16) & 1u)) >> 16);
}
__device__ __forceinline__ float bflo(unsigned u) { return __uint_as_float(u << 16); }
__device__ __forceinline__ float bfhi(unsigned u) { return __uint_as_float(u & 0xffff0000u); }
__device__ __forceinline__ float bfhiraw(unsigned u) { return __uint_as_float(u); }  // hi + 2^-9 noise
__device__ __forceinline__ float bfval(ushort_t u) { return __uint_as_float(((unsigned)u) << 16); }

// ---------------- CSR build ----------------
// deg[] is memset to 0 on the host side; histogram counts edges only.
__global__ void k_deg_edges(const int* __restrict__ ei, int* __restrict__ deg,
                            int* __restrict__ eofs, int E) {
    int e = blockIdx.x * blockDim.x + threadIdx.x;
    if (e < E) eofs[e] = atomicAdd(&deg[ei[E + e]], 1);
}

__global__ __launch_bounds__(256) void k_scan1(const int* __restrict__ deg, int* __restrict__ rs,
                                               int* __restrict__ bsum, int N) {
    __shared__ int s[256];
    int t = threadIdx.x;
    int base = blockIdx.x * 1024;
    int i0 = base + t * 4;
    // +1 per node = the self loop (slot 0 of each segment)
    int d0 = (i0 + 0 < N) ? deg[i0 + 0] + 1 : 0;
    int d1 = (i0 + 1 < N) ? deg[i0 + 1] + 1 : 0;
    int d2 = (i0 + 2 < N) ? deg[i0 + 2] + 1 : 0;
    int d3 = (i0 + 3 < N) ? deg[i0 + 3] + 1 : 0;
    int s0 = d0, s1 = s0 + d1, s2 = s1 + d2, s3 = s2 + d3;
    int tsum = s3;
    s[t] = tsum;
    __syncthreads();
    for (int off = 1; off < 256; off <<= 1) {
        int v = (t >= off) ? s[t - off] : 0;
        __syncthreads();
        s[t] += v;
        __syncthreads();
    }
    int excl = s[t] - tsum;
    if (i0 + 0 < N) rs[1 + i0 + 0] = excl + s0;
    if (i0 + 1 < N) rs[1 + i0 + 1] = excl + s1;
    if (i0 + 2 < N) rs[1 + i0 + 2] = excl + s2;
    if (i0 + 3 < N) rs[1 + i0 + 3] = excl + s3;
    if (t == 0) bsum[blockIdx.x] = s[255];
}

__global__ __launch_bounds__(256) void k_scan2(const int* __restrict__ bsum,
                                               int* __restrict__ boff, int NB) {
    __shared__ int s[256];
    int t = threadIdx.x;
    int orig = (t < NB) ? bsum[t] : 0;
    s[t] = orig;
    __syncthreads();
    for (int off = 1; off < 256; off <<= 1) {
        int v = (t >= off) ? s[t - off] : 0;
        __syncthreads();
        s[t] += v;
        __syncthreads();
    }
    if (t < NB) boff[t] = s[t] - orig;  // exclusive
}

__global__ void k_scan3(int* __restrict__ rs, const int* __restrict__ boff, int N) {
    int i = blockIdx.x * blockDim.x + threadIdx.x;
    if (i == 0) rs[0] = 0;
    if (i < N) rs[1 + i] += boff[i >> 10];
}

// slice-filtered, atomic-free scatter (csr lines stay in one XCD L2).
// self loop -> slot 0; edge e -> slot 1 + eofs[e].
__global__ __launch_bounds__(256) void k_scatter(const int* __restrict__ ei,
                                                 const int* __restrict__ eofs,
                                                 const int* __restrict__ rs,
                                                 int* __restrict__ csr,
                                                 int E, int Etot, int cohortBlocks) {
    int c = blockIdx.x & 7;
    int pb = blockIdx.x >> 3;
    int tid = pb * 256 + threadIdx.x;
    int stride = cohortBlocks * 256;
    for (int e = tid; e < Etot; e += stride) {
        int dst = (e < E) ? ei[E + e] : (e - E);
        if (((dst >> 13) & 7) != c) continue;
        int src, ofs;
        if (e < E) { src = ei[e]; ofs = 1 + eofs[e]; } else { src = dst; ofs = 0; }
        csr[rs[dst] + ofs] = src;
    }
}

// ---------------- dense kernels (register-tiled) ----------------

// h0 = relu(x @ W0 + b0), stored bf16; x[N,128], W0[128,64]. 64 nodes/block.
__global__ __launch_bounds__(256) void k_gemm1(const float* __restrict__ x,
                                               const float* __restrict__ W0,
                                               const float* __restrict__ b0,
                                               unsigned* __restrict__ h0b, int N) {
    __shared__ float wl[128 * 64];   // [k][c]
    __shared__ float al[64 * 132];   // [node][k] padded
    int t = threadIdx.x;
    int n0 = blockIdx.x * 64;
    const float4* wg = (const float4*)W0;
    float4* wl4 = (float4*)wl;
#pragma unroll
    for (int i = 0; i < 8; ++i) wl4[t + i * 256] = wg[t + i * 256];
#pragma unroll
    for (int i = 0; i < 8; ++i) {
        int f = t + i * 256;
        int node = f >> 5, q = f & 31;
        int ng = n0 + node; if (ng > N - 1) ng = N - 1;
        float4 v = ((const float4*)x)[(size_t)ng * 32 + q];
        *(float4*)&al[node * 132 + q * 4] = v;
    }
    __syncthreads();
    int colg = t & 15;   // cols colg*4..+3
    int rowg = t >> 4;   // rows rowg*4..+3
    float4 acc[4];
#pragma unroll
    for (int j = 0; j < 4; ++j) acc[j] = make_float4(0.f, 0.f, 0.f, 0.f);
    for (int k4 = 0; k4 < 128; k4 += 4) {
        float4 w0 = *(float4*)&wl[(k4 + 0) * 64 + colg * 4];
        float4 w1 = *(float4*)&wl[(k4 + 1) * 64 + colg * 4];
        float4 w2 = *(float4*)&wl[(k4 + 2) * 64 + colg * 4];
        float4 w3 = *(float4*)&wl[(k4 + 3) * 64 + colg * 4];
#pragma unroll
        for (int j = 0; j < 4; ++j) {
            float4 a = *(float4*)&al[(rowg * 4 + j) * 132 + k4];
            acc[j].x += a.x * w0.x + a.y * w1.x + a.z * w2.x + a.w * w3.x;
            acc[j].y += a.x * w0.y + a.y * w1.y + a.z * w2.y + a.w * w3.y;
            acc[j].z += a.x * w0.z + a.y * w1.z + a.z * w2.z + a.w * w3.z;
            acc[j].w += a.x * w0.w + a.y * w1.w + a.z * w2.w + a.w * w3.w;
        }
    }
    float4 bb = ((const float4*)b0)[colg];
#pragma unroll
    for (int j = 0; j < 4; ++j) {
        int n = n0 + rowg * 4 + j;
        if (n < N) {
            float rx = fmaxf(acc[j].x + bb.x, 0.f);
            float ry = fmaxf(acc[j].y + bb.y, 0.f);
            float rz = fmaxf(acc[j].z + bb.z, 0.f);
            float rw = fmaxf(acc[j].w + bb.w, 0.f);
            uint2 pr; pr.x = bfpack(rx, ry); pr.y = bfpack(rz, rw);
            ((uint2*)h0b)[(size_t)n * 16 + colg] = pr;  // 64 bf16 = 16 uint2/row
        }
    }
}

// h1 = h0 @ W1 (stored bf16) + fused att1 dots. h0b[N,64] bf16, W1[64,128].
__global__ __launch_bounds__(256) void k_gemm2(const unsigned* __restrict__ h0b,
                                               const float* __restrict__ W1,
                                               const float* __restrict__ as_g,
                                               const float* __restrict__ ad_g,
                                               ushort_t* __restrict__ h1b,
                                               float* __restrict__ as1,
                                               float* __restrict__ ad1, int N) {
    __shared__ float wl[64 * 128];  // [k][c]
    __shared__ float al[64 * 68];   // [node][k] padded
    int t = threadIdx.x;
    int n0 = blockIdx.x * 64;
    const float4* wg = (const float4*)W1;
    float4* wl4 = (float4*)wl;
#pragma unroll
    for (int i = 0; i < 8; ++i) wl4[t + i * 256] = wg[t + i * 256];
#pragma unroll
    for (int i = 0; i < 2; ++i) {
        int f = t + i * 256;          // 0..511
        int node = f >> 3, q = f & 7; // row = 32 uints = 8 uint4
        int ng = n0 + node; if (ng > N - 1) ng = N - 1;
        uint4 u = ((const uint4*)h0b)[(size_t)ng * 8 + q];
        float* dst = &al[node * 68 + q * 8];
        dst[0] = bflo(u.x); dst[1] = bfhi(u.x);
        dst[2] = bflo(u.y); dst[3] = bfhi(u.y);
        dst[4] = bflo(u.z); dst[5] = bfhi(u.z);
        dst[6] = bflo(u.w); dst[7] = bfhi(u.w);
    }
    __syncthreads();
    int colg = t & 31;   // cols colg*4..+3 (head = colg>=16)
    int rowg = t >> 5;   // rows rowg*8..+7
    float4 acc[8];
#pragma unroll
    for (int j = 0; j < 8; ++j) acc[j] = make_float4(0.f, 0.f, 0.f, 0.f);
    for (int k4 = 0; k4 < 64; k4 += 4) {
        float4 w0 = *(float4*)&wl[(k4 + 0) * 128 + colg * 4];
        float4 w1 = *(float4*)&wl[(k4 + 1) * 128 + colg * 4];
        float4 w2 = *(float4*)&wl[(k4 + 2) * 128 + colg * 4];
        float4 w3 = *(float4*)&wl[(k4 + 3) * 128 + colg * 4];
#pragma unroll
        for (int j = 0; j < 8; ++j) {
            float4 a = *(float4*)&al[(rowg * 8 + j) * 68 + k4];
            acc[j].x += a.x * w0.x + a.y * w1.x + a.z * w2.x + a.w * w3.x;
            acc[j].y += a.x * w0.y + a.y * w1.y + a.z * w2.y + a.w * w3.y;
            acc[j].z += a.x * w0.z + a.y * w1.z + a.z * w2.z + a.w * w3.z;
            acc[j].w += a.x * w0.w + a.y * w1.w + a.z * w2.w + a.w * w3.w;
        }
    }
    float4 asv = ((const float4*)as_g)[colg];
    float4 adv = ((const float4*)ad_g)[colg];
    float ps[8], pd[8];
#pragma unroll
    for (int j = 0; j < 8; ++j) {
        ps[j] = acc[j].x * asv.x + acc[j].y * asv.y + acc[j].z * asv.z + acc[j].w * asv.w;
        pd[j] = acc[j].x * adv.x + acc[j].y * adv.y + acc[j].z * adv.z + acc[j].w * adv.w;
    }
    for (int o = 1; o < 16; o <<= 1) {
#pragma unroll
        for (int j = 0; j < 8; ++j) {
            ps[j] += __shfl_xor(ps[j], o);
            pd[j] += __shfl_xor(pd[j], o);
        }
    }
#pragma unroll
    for (int j = 0; j < 8; ++j) {
        int n = n0 + rowg * 8 + j;
        if (n < N) {
            uint2 pr;
            pr.x = bfpack(acc[j].x, acc[j].y);
            pr.y = bfpack(acc[j].z, acc[j].w);
            ((uint2*)h1b)[(size_t)n * 32 + colg] = pr;  // 32 uint2 per row
        }
    }
    int lane = t & 63;
    if ((lane & 15) == 0) {
        int head = (lane >> 4) & 1;
#pragma unroll
        for (int j = 0; j < 8; ++j) {
            int n = n0 + rowg * 8 + j;
            if (n < N) {
                as1[n * 2 + head] = ps[j];
                ad1[n * 2 + head] = pd[j];
            }
        }
    }
}

// ---- layer-1 fused: single-pass softmax (deg<=64), 4-edge dwordx4 loop ----
// stashA padded to 136 (head offset 68): heads hit disjoint LDS banks
// (R11's offset 64 = 512B aliased banks -> 925k conflicts).
__global__ __launch_bounds__(256) void k_node_l1(const int* __restrict__ rs,
                                                 const int* __restrict__ csr,
                                                 const ushort_t* __restrict__ h1b,
                                                 const float* __restrict__ as1,
                                                 const float* __restrict__ ad1,
                                                 const float* __restrict__ b1,
                                                 unsigned* __restrict__ aggb, int N) {
    __shared__ float2 stashA[4][136];  // [wid][head*68+edge]
    int wid = threadIdx.x >> 6;
    int lane = threadIdx.x & 63;
    int n = (blockIdx.x * 256 + threadIdx.x) >> 6;
    if (n >= N) return;
    int row = rs[n], end = rs[n + 1];
    int deg = end - row;
    float2 adv = ((const float2*)ad1)[n];
    const float2* asp = (const float2*)as1;
    const char* h1base = (const char*)h1b;
    int eg = lane >> 4;                 // 0..3
    int fl = lane & 15;                 // 0..15
    int head_off = (fl >= 8) ? 68 : 0;
    int flbase = fl * 16;               // byte offset within 256B row
    float acc[8] = {0.f, 0.f, 0.f, 0.f, 0.f, 0.f, 0.f, 0.f};
    float inv0, inv1;
    if (deg <= 64) {
        // ---- fast path: single pass, unnormalized p; scale in epilogue ----
        bool act = lane < deg;
        int src = act ? csr[row + lane] : 0;
        float2 av = asp[src];
        float e0 = av.x + adv.x, e1 = av.y + adv.y;
        e0 = e0 > 0.f ? e0 : NEG_SLOPE * e0;
        e1 = e1 > 0.f ? e1 : NEG_SLOPE * e1;
        if (!act) { e0 = -INFINITY; e1 = -INFINITY; }
        float m0 = wmax(e0), m1 = wmax(e1);
        float p0 = act ? __expf(e0 - m0) : 0.f;
        float p1 = act ? __expf(e1 - m1) : 0.f;
        inv0 = __builtin_amdgcn_rcpf(wsum(p0));
        inv1 = __builtin_amdgcn_rcpf(wsum(p1));
        stashA[wid][lane] = make_float2(__int_as_float(src), p0);
        stashA[wid][68 + lane] = make_float2(__int_as_float(src), p1);
        for (int j = 0; j < deg; j += 4) {   // entries >= deg have p=0, src=0
            float2 sa = stashA[wid][head_off + j + eg];
            int sj = __float_as_int(sa.x);
            float aj = sa.y;
            uint4 u = *(const uint4*)(h1base + (((unsigned)sj) << 8) + flbase);
            acc[0] += bflo(u.x) * aj; acc[1] += bfhiraw(u.x) * aj;
            acc[2] += bflo(u.y) * aj; acc[3] += bfhiraw(u.y) * aj;
            acc[4] += bflo(u.z) * aj; acc[5] += bfhiraw(u.z) * aj;
            acc[6] += bflo(u.w) * aj; acc[7] += bfhiraw(u.w) * aj;
        }
    } else {
        // ---- slow path (deg>64; never taken on this input): two-pass,
        // global re-gather, normalized alpha in stash ----
        inv0 = 1.f; inv1 = 1.f;
        float m0 = -INFINITY, m1 = -INFINITY, l0 = 0.f, l1 = 0.f;
        for (int base = row; base < end; base += 64) {
            int idx = base + lane;
            bool act = idx < end;
            int src = act ? csr[idx] : 0;
            float2 av = asp[src];
            float e0 = av.x + adv.x, e1 = av.y + adv.y;
            e0 = e0 > 0.f ? e0 : NEG_SLOPE * e0;
            e1 = e1 > 0.f ? e1 : NEG_SLOPE * e1;
            if (!act) { e0 = -INFINITY; e1 = -INFINITY; }
            float m0n = fmaxf(m0, wmax(e0));
            float m1n = fmaxf(m1, wmax(e1));
            float p0 = act ? __expf(e0 - m0n) : 0.f;
            float p1 = act ? __expf(e1 - m1n) : 0.f;
            l0 = l0 * __expf(m0 - m0n) + wsum(p0);
            l1 = l1 * __expf(m1 - m1n) + wsum(p1);
            m0 = m0n; m1 = m1n;
        }
        float r0 = __builtin_amdgcn_rcpf(l0);
        float r1 = __builtin_amdgcn_rcpf(l1);
        for (int base = row; base < end; base += 64) {
            int idx = base + lane;
            bool act = idx < end;
            int src = act ? csr[idx] : 0;
            float2 av = asp[src];
            float e0 = av.x + adv.x, e1 = av.y + adv.y;
            e0 = e0 > 0.f ? e0 : NEG_SLOPE * e0;
            e1 = e1 > 0.f ? e1 : NEG_SLOPE * e1;
            float a0 = act ? __expf(e0 - m0) * r0 : 0.f;
            float a1 = act ? __expf(e1 - m1) * r1 : 0.f;
            stashA[wid][lane] = make_float2(__int_as_float(src), a0);
            stashA[wid][68 + lane] = make_float2(__int_as_float(src), a1);
            int cnt = min(64, end - base);
            for (int j = 0; j < cnt; j += 4) {
                float2 sa = stashA[wid][head_off + j + eg];
                int sj = __float_as_int(sa.x);
                float aj = sa.y;
                uint4 u = *(const uint4*)(h1base + (((unsigned)sj) << 8) + flbase);
                acc[0] += bflo(u.x) * aj; acc[1] += bfhiraw(u.x) * aj;
                acc[2] += bflo(u.y) * aj; acc[3] += bfhiraw(u.y) * aj;
                acc[4] += bflo(u.z) * aj; acc[5] += bfhiraw(u.z) * aj;
                acc[6] += bflo(u.w) * aj; acc[7] += bfhiraw(u.w) * aj;
            }
        }
    }
    // merge the 4 edge subgroups (eg = lane bits 4,5)
#pragma unroll
    for (int i = 0; i < 8; ++i) {
        acc[i] += __shfl_xor(acc[i], 16);
        acc[i] += __shfl_xor(acc[i], 32);
    }
    if (lane < 16) {
        float inv = (lane >= 8) ? inv1 : inv0;
        float4 ba = ((const float4*)b1)[lane * 2];
        float4 bb4 = ((const float4*)b1)[lane * 2 + 1];
        float v[8];
        v[0] = acc[0] * inv + ba.x;  v[1] = acc[1] * inv + ba.y;
        v[2] = acc[2] * inv + ba.z;  v[3] = acc[3] * inv + ba.w;
        v[4] = acc[4] * inv + bb4.x; v[5] = acc[5] * inv + bb4.y;
        v[6] = acc[6] * inv + bb4.z; v[7] = acc[7] * inv + bb4.w;
#pragma unroll
        for (int i = 0; i < 8; ++i) v[i] = v[i] > 0.f ? v[i] : __expf(v[i]) - 1.f;
        uint4 pk;
        pk.x = bfpack(v[0], v[1]); pk.y = bfpack(v[2], v[3]);
        pk.z = bfpack(v[4], v[5]); pk.w = bfpack(v[6], v[7]);
        ((uint4*)aggb)[(size_t)n * 16 + lane] = pk;
    }
}

// h2 = agg1 @ W2 (agg bf16 in, h2 bf16 out) + att2 dots. 64 nodes/block.
__global__ __launch_bounds__(256, 4) void k_node2(const unsigned* __restrict__ aggb,
                                                  const float* __restrict__ W2,
                                                  const float* __restrict__ as_g,
                                                  const float* __restrict__ ad_g,
                                                  ushort_t* __restrict__ h2b,
                                                  float* __restrict__ a_s,
                                                  float* __restrict__ a_d, int N) {
    __shared__ float al[64 * 132];   // [node][k] padded
    __shared__ float w2t[20 * 132];  // [c][k] padded, cols 18,19 zero
    int t = threadIdx.x;
    int n0 = blockIdx.x * 64;
#pragma unroll
    for (int i = 0; i < 4; ++i) {
        int f = t + i * 256;            // 0..1023
        int node = f >> 4, q = f & 15;  // row = 64 uints = 16 uint4
        int ng = n0 + node; if (ng > N - 1) ng = N - 1;
        uint4 u = ((const uint4*)aggb)[(size_t)ng * 16 + q];
        float* dst = &al[node * 132 + q * 8];
        dst[0] = bflo(u.x); dst[1] = bfhi(u.x);
        dst[2] = bflo(u.y); dst[3] = bfhi(u.y);
        dst[4] = bflo(u.z); dst[5] = bfhi(u.z);
        dst[6] = bflo(u.w); dst[7] = bfhi(u.w);
    }
    for (int i = t; i < 2560; i += 256) {
        int c = i >> 7, k = i & 127;
        w2t[c * 132 + k] = (c < 18) ? W2[k * 18 + c] : 0.f;
    }
    __syncthreads();
    int node = t >> 2;
    int cq = t & 3;
    int c0 = cq * 5;  // cols c0..c0+4 (cq==3: cols 15..19, 18/19 dead)
    int n = n0 + node;
    float acc[5] = {0.f, 0.f, 0.f, 0.f, 0.f};
#pragma unroll 2
    for (int k4 = 0; k4 < 128; k4 += 4) {
        float4 a = *(float4*)&al[node * 132 + k4];
#pragma unroll
        for (int i = 0; i < 5; ++i) {
            float4 w = *(float4*)&w2t[(c0 + i) * 132 + k4];
            acc[i] += a.x * w.x + a.y * w.y + a.z * w.z + a.w * w.w;
        }
    }
    float ps = 0.f, pd = 0.f;
#pragma unroll
    for (int i = 0; i < 5; ++i) {
        int c = c0 + i;
        float asv = (c < 18) ? as_g[c] : 0.f;
        float adv = (c < 18) ? ad_g[c] : 0.f;
        ps += acc[i] * asv;
        pd += acc[i] * adv;
    }
    ps += __shfl_xor(ps, 1); ps += __shfl_xor(ps, 2);
    pd += __shfl_xor(pd, 1); pd += __shfl_xor(pd, 2);
    if (n < N) {
#pragma unroll
        for (int i = 0; i < 5; ++i) {
            int c = c0 + i;
            if (c < 18) h2b[(size_t)n * 24 + c] = bf16of(acc[i]);
        }
        if (cq == 0) { a_s[n] = ps; a_d[n] = pd; }
    }
}

// ---- layer-2 fused: single-pass (deg<=64) stash p; phase B no exp ----
__global__ __launch_bounds__(256) void k_node_l2(const int* __restrict__ rs,
                                                 const int* __restrict__ csr,
                                                 const ushort_t* __restrict__ h2b,
                                                 const float* __restrict__ as2,
                                                 const float* __restrict__ ad2,
                                                 const float* __restrict__ b2,
                                                 float* __restrict__ out, int N) {
    __shared__ float2 stash[4][64];  // (src bits, p) fast path
    int wid = threadIdx.x >> 6;
    int lane = threadIdx.x & 63;
    int n = (blockIdx.x * 256 + threadIdx.x) >> 6;
    if (n >= N) return;
    int row = rs[n], end = rs[n + 1];
    int deg = end - row;
    float adn = ad2[n];
    int g = lane / 21;            // 0..3 (lane 63 -> g=3, acc discarded)
    int c = lane - g * 21;        // 0..20
    int cc = c < 18 ? c : 17;     // clamp for safe loads
    float acc = 0.f;
    float post;
    if (deg <= 64) {
        // ---- fast: single pass, unnormalized p; scale after group-sum ----
        bool act = lane < deg;
        int src = act ? csr[row + lane] : 0;
        float e = as2[src] + adn;
        e = e > 0.f ? e : NEG_SLOPE * e;
        if (!act) e = -INFINITY;
        float m = wmax(e);
        float p = act ? __expf(e - m) : 0.f;
        post = __builtin_amdgcn_rcpf(wsum(p));
        stash[wid][lane] = make_float2(__int_as_float(src), p);
        for (int o = g; o < deg; o += 3) {
            float2 se = stash[wid][o];
            int src2 = __float_as_int(se.x);
            acc += se.y * bfval(h2b[(size_t)src2 * 24 + cc]);
        }
    } else {
        // ---- slow path (deg>64; never taken on this input): two-pass,
        // global re-gather ----
        post = 1.f;
        float m = -INFINITY, l = 0.f;
        for (int base = row; base < end; base += 64) {
            int idx = base + lane;
            bool act = idx < end;
            int src = act ? csr[idx] : 0;
            float e = as2[src] + adn;
            e = e > 0.f ? e : NEG_SLOPE * e;
            if (!act) e = -INFINITY;
            float mn = fmaxf(m, wmax(e));
            float p = act ? __expf(e - mn) : 0.f;
            l = l * __expf(m - mn) + wsum(p);
            m = mn;
        }
        float invl = __builtin_amdgcn_rcpf(l);
        for (int pos = row + g; pos < end; pos += 3) {
            int src = csr[pos];
            float e = as2[src] + adn;
            e = e > 0.f ? e : NEG_SLOPE * e;
            float alpha = __expf(e - m) * invl;
            acc += alpha * bfval(h2b[(size_t)src * 24 + cc]);
        }
    }
    // group-sum into lanes 0..17: both shfls read pre-mutation acc
    float t1 = __shfl(acc, (lane + 21) & 63);
    float t2 = __shfl(acc, (lane + 42) & 63);
    acc += t1 + t2;
    float bb = (lane < 18) ? b2[lane] : 0.f;
    float v = acc * post + bb;
    // ---- lane-parallel log-softmax over lanes 0..17 (32-lane xor net) ----
    float tmx = (lane < 18) ? v : -INFINITY;
    for (int o = 16; o; o >>= 1) tmx = fmaxf(tmx, __shfl_xor(tmx, o));
    float s = (lane < 18) ? __expf(v - tmx) : 0.f;
    for (int o = 16; o; o >>= 1) s += __shfl_xor(s, o);
    float lse = tmx + __logf(s);
    if (lane < 18) out[(size_t)n * 18 + lane] = v - lse;
}

extern "C" void kernel_launch(void* const* d_in, const int* in_sizes, int n_in,
                              void* d_out, int out_size, void* d_ws, size_t ws_size,
                              hipStream_t stream) {
    const float* x      = (const float*)d_in[0];
    const int*   ei     = (const int*)d_in[1];
    const float* W0     = (const float*)d_in[2];
    const float* b0     = (const float*)d_in[3];
    const float* W1     = (const float*)d_in[4];
    const float* att_s1 = (const float*)d_in[5];
    const float* att_d1 = (const float*)d_in[6];
    const float* b1     = (const float*)d_in[7];
    const float* W2     = (const float*)d_in[8];
    const float* att_s2 = (const float*)d_in[9];
    const float* att_d2 = (const float*)d_in[10];
    const float* b2     = (const float*)d_in[11];

    const int N = in_sizes[0] / 128;
    const int E = in_sizes[1] / 2;
    const int Etot = E + N;
    const int NB = (N + 1023) / 1024;  // scan blocks (<= 256)
    const int NBLK = (N + 63) / 64;    // dense tiles

    // workspace carve-up (~100 MB)
    char* w = (char*)d_ws;
    unsigned* h0b  = (unsigned*)w; w += (size_t)N * 64 * 2;   // bf16 x 64
    ushort_t* h1b  = (ushort_t*)w; w += (size_t)N * 128 * 2;
    unsigned* aggb = (unsigned*)w; w += (size_t)N * 128 * 2;  // bf16 x 128
    float* as1     = (float*)w;    w += (size_t)N * 2 * 4;
    float* ad1     = (float*)w;    w += (size_t)N * 2 * 4;
    ushort_t* h2b  = (ushort_t*)w; w += (size_t)N * 24 * 2;
    float* as2     = (float*)w;    w += (size_t)N * 4;
    float* ad2     = (float*)w;    w += (size_t)N * 4;
    int* deg       = (int*)w;      w += (size_t)N * 4;
    int* rs        = (int*)w;      w += (size_t)(N + 1) * 4;
    int* bsum      = (int*)w;      w += (size_t)256 * 4;
    int* boff      = (int*)w;      w += (size_t)256 * 4;
    int* eofs      = (int*)w;      w += (size_t)E * 4;
    int* csr       = (int*)w;      w += (size_t)Etot * 4;

    float* out = (float*)d_out;

    // ---- CSR build ----
    hipMemsetAsync(deg, 0, (size_t)N * 4, stream);
    k_deg_edges<<<(E + 255) / 256, 256, 0, stream>>>(ei, deg, eofs, E);
    k_scan1<<<NB, 256, 0, stream>>>(deg, rs, bsum, N);
    k_scan2<<<1, 256, 0, stream>>>(bsum, boff, NB);
    k_scan3<<<(N + 255) / 256, 256, 0, stream>>>(rs, boff, N);
    const int cohortBlocks = 128;
    k_scatter<<<8 * cohortBlocks, 256, 0, stream>>>(ei, eofs, rs, csr, E, Etot, cohortBlocks);

    // ---- dense ----
    k_gemm1<<<NBLK, 256, 0, stream>>>(x, W0, b0, h0b, N);
    k_gemm2<<<NBLK, 256, 0, stream>>>(h0b, W1, att_s1, att_d1, h1b, as1, ad1, N);

    // ---- layer 1 fused edge pass ----
    k_node_l1<<<(N * 64 + 255) / 256, 256, 0, stream>>>(rs, csr, h1b, as1, ad1, b1, aggb, N);

    // ---- layer 2 dense + fused edge pass ----
    k_node2<<<NBLK, 256, 0, stream>>>(aggb, W2, att_s2, att_d2, h2b, as2, ad2, N);
    k_node_l2<<<(N * 64 + 255) / 256, 256, 0, stream>>>(rs, csr, h2b, as2, ad2, b2, out, N);
}